// Round 4
// baseline (462.972 us; speedup 1.0000x reference)
//
#include <hip/hip_runtime.h>

// L2Q attention, fp16-MFMA, hi/lo split on q/k path AND proj GEMM.
// B=8, N=1024, C=768, H=12, d=64, 3C=2304, M=B*N=8192.
// R4: proj 3-term split (dominant error source); outh fp32; consistent
//     P-denominator; v-third of qkv GEMM 1-term; attn barrier-free.

typedef _Float16 f16x8 __attribute__((ext_vector_type(8)));
typedef _Float16 f16x4 __attribute__((ext_vector_type(4)));
typedef float f32x4 __attribute__((ext_vector_type(4)));

#define NB 8
#define NN 1024
#define NC 768
#define NH 12
#define ND 64
#define TC 2304
#define NM 8192

// intra-wave LDS ordering: wait for DS ops + stop compiler reordering.
#define LDS_FENCE() asm volatile("s_waitcnt lgkmcnt(0)" ::: "memory")

__device__ __forceinline__ void async16(const void* g, void* l) {
    __builtin_amdgcn_global_load_lds(
        (const __attribute__((address_space(1))) void*)g,
        (__attribute__((address_space(3))) void*)l, 16, 0, 0);
}

// ---------------- fp32 -> fp16 hi/lo split ----------------
__global__ void cvt_split_f32(const float* __restrict__ s, _Float16* __restrict__ hi,
                              _Float16* __restrict__ lo, int n4) {
    int i = blockIdx.x * 256 + threadIdx.x;
    if (i < n4) {
        float4 v = ((const float4*)s)[i];
        f16x4 h, l;
        h[0] = (_Float16)v.x; l[0] = (_Float16)(v.x - (float)h[0]);
        h[1] = (_Float16)v.y; l[1] = (_Float16)(v.y - (float)h[1]);
        h[2] = (_Float16)v.z; l[2] = (_Float16)(v.z - (float)h[2]);
        h[3] = (_Float16)v.w; l[3] = (_Float16)(v.w - (float)h[3]);
        ((f16x4*)hi)[i] = h;
        ((f16x4*)lo)[i] = l;
    }
}

// ---------------- qkv GEMM: C[8192,2304] = X * Wqkv^T ----------------
// q/k columns (n0<1536): 3-term split. v columns: 1-term (errors convex-average in PV).
// A staged from fp32 X with in-register split; B via global_load_lds(16B).
__global__ __launch_bounds__(256) void gemm_qkv(
    const float* __restrict__ X,
    const _Float16* __restrict__ Bh, const _Float16* __restrict__ Bl,
    _Float16* __restrict__ qh, _Float16* __restrict__ ql,
    _Float16* __restrict__ kh, _Float16* __restrict__ kl,
    _Float16* __restrict__ vt16)
{
    __shared__ __align__(16) _Float16 sAh[128 * 32];
    __shared__ __align__(16) _Float16 sAl[128 * 32];
    __shared__ __align__(16) _Float16 sBh[128 * 32];
    __shared__ __align__(16) _Float16 sBl[128 * 32];
    const int tid = threadIdx.x;
    const int lane = tid & 63, wv = tid >> 6;
    const int quad = lane >> 4, l16 = lane & 15;
    const int wm = (wv >> 1) * 64, wn = (wv & 1) * 64;
    const int m0 = blockIdx.x * 128, n0 = blockIdx.y * 128;
    const bool is_v = (n0 >= 2 * NC);   // v third: 1-term suffices

    f32x4 acc[4][4] = {};

    for (int k0 = 0; k0 < NC; k0 += 32) {
#pragma unroll
        for (int i = 0; i < 2; i++) {
            int c = tid + i * 256;       // chunk 0..511
            int r = c >> 2, kc = c & 3;  // row, 8-elem chunk within row
            const float4* pa = (const float4*)(X + (size_t)(m0 + r) * NC + k0 + kc * 8);
            float4 v0 = pa[0], v1 = pa[1];
            f16x8 hi8, lo8;
            hi8[0] = (_Float16)v0.x; lo8[0] = (_Float16)(v0.x - (float)hi8[0]);
            hi8[1] = (_Float16)v0.y; lo8[1] = (_Float16)(v0.y - (float)hi8[1]);
            hi8[2] = (_Float16)v0.z; lo8[2] = (_Float16)(v0.z - (float)hi8[2]);
            hi8[3] = (_Float16)v0.w; lo8[3] = (_Float16)(v0.w - (float)hi8[3]);
            hi8[4] = (_Float16)v1.x; lo8[4] = (_Float16)(v1.x - (float)hi8[4]);
            hi8[5] = (_Float16)v1.y; lo8[5] = (_Float16)(v1.y - (float)hi8[5]);
            hi8[6] = (_Float16)v1.z; lo8[6] = (_Float16)(v1.z - (float)hi8[6]);
            hi8[7] = (_Float16)v1.w; lo8[7] = (_Float16)(v1.w - (float)hi8[7]);
            *(f16x8*)(sAh + c * 8) = hi8;
            if (!is_v) *(f16x8*)(sAl + c * 8) = lo8;
            size_t goB = (size_t)(n0 + r) * NC + k0 + kc * 8;
            async16(Bh + goB, sBh + c * 8);
            if (!is_v) async16(Bl + goB, sBl + c * 8);
        }
        __syncthreads();
        f16x8 ah[4], bh[4];
#pragma unroll
        for (int t = 0; t < 4; t++) {
            ah[t] = *(const f16x8*)(sAh + (wm + t * 16 + l16) * 32 + quad * 8);
            bh[t] = *(const f16x8*)(sBh + (wn + t * 16 + l16) * 32 + quad * 8);
        }
        if (!is_v) {
            f16x8 al[4], bl[4];
#pragma unroll
            for (int t = 0; t < 4; t++) {
                al[t] = *(const f16x8*)(sAl + (wm + t * 16 + l16) * 32 + quad * 8);
                bl[t] = *(const f16x8*)(sBl + (wn + t * 16 + l16) * 32 + quad * 8);
            }
#pragma unroll
            for (int i = 0; i < 4; i++)
#pragma unroll
                for (int j = 0; j < 4; j++) {
                    acc[i][j] = __builtin_amdgcn_mfma_f32_16x16x32_f16(ah[i], bh[j], acc[i][j], 0, 0, 0);
                    acc[i][j] = __builtin_amdgcn_mfma_f32_16x16x32_f16(al[i], bh[j], acc[i][j], 0, 0, 0);
                    acc[i][j] = __builtin_amdgcn_mfma_f32_16x16x32_f16(ah[i], bl[j], acc[i][j], 0, 0, 0);
                }
        } else {
#pragma unroll
            for (int i = 0; i < 4; i++)
#pragma unroll
                for (int j = 0; j < 4; j++)
                    acc[i][j] = __builtin_amdgcn_mfma_f32_16x16x32_f16(ah[i], bh[j], acc[i][j], 0, 0, 0);
        }
        __syncthreads();
    }

    // epilogue: q,k as hi/lo pairs [B,H,N,d]; v^T fp16 [B,H,d,N]
#pragma unroll
    for (int i = 0; i < 4; i++) {
#pragma unroll
        for (int j = 0; j < 4; j++) {
#pragma unroll
            for (int r = 0; r < 4; r++) {
                int row = m0 + wm + i * 16 + quad * 4 + r;
                int col = n0 + wn + j * 16 + l16;
                float fv = acc[i][j][r];
                int b = row >> 10, nr = row & 1023;
                int which = col / NC;
                int w2 = col - which * NC;
                int h = w2 >> 6, dd = w2 & 63;
                int bhd = b * NH + h;
                size_t idx = ((size_t)(bhd * NN + nr)) * ND + dd;
                if (which == 0) {
                    _Float16 hv = (_Float16)fv;
                    qh[idx] = hv;
                    ql[idx] = (_Float16)(fv - (float)hv);
                } else if (which == 1) {
                    _Float16 hv = (_Float16)fv;
                    kh[idx] = hv;
                    kl[idx] = (_Float16)(fv - (float)hv);
                } else {
                    vt16[((size_t)(bhd * ND + dd)) * NN + nr] = (_Float16)fv;
                }
            }
        }
    }
}

// ---------------- fused quadratic-ReLU attention ----------------
// grid (8 q-tiles, 96 bh), 256 threads = 4 waves; wave handles 32 q-rows.
// Barrier-free: sP is per-wave private; intra-wave DS ordering via LDS_FENCE.
// Denominator accumulates the fp16-ROUNDED weights (exact convex combination).
__global__ __launch_bounds__(256) void attn_kernel(
    const _Float16* __restrict__ qhp, const _Float16* __restrict__ qlp,
    const _Float16* __restrict__ khp, const _Float16* __restrict__ klp,
    const _Float16* __restrict__ vt16, float* __restrict__ outh32,
    const float* __restrict__ alpha, const float* __restrict__ beta,
    const float* __restrict__ gamma)
{
    const int qt = blockIdx.x, bh = blockIdx.y;
    const int b = bh / NH, h = bh - b * NH;
    const int tid = threadIdx.x, lane = tid & 63, wv = tid >> 6;
    const int quad = lane >> 4, l16 = lane & 15;
    const float a2 = alpha[h] * 0.015625f;   // alpha * SCALE^2
    const float b1 = beta[h] * 0.125f;       // beta * SCALE
    const float g0 = gamma[h];

    __shared__ __align__(16) _Float16 sP[4][32 * 136];  // per-wave P, stride 136 (pad)

    const size_t qoff = ((size_t)(bh * NN + qt * 128)) * ND;
    const _Float16* Qh = qhp + qoff;
    const _Float16* Ql = qlp + qoff;
    const _Float16* Kh = khp + (size_t)bh * NN * ND;
    const _Float16* Kl = klp + (size_t)bh * NN * ND;
    const _Float16* Vb = vt16 + (size_t)bh * ND * NN;

    // Q fragments (hi and lo): 2 m-tiles x 2 k-steps
    f16x8 qfh[2][2], qfl[2][2];
#pragma unroll
    for (int mt = 0; mt < 2; mt++)
#pragma unroll
        for (int ks = 0; ks < 2; ks++) {
            size_t o = (size_t)(wv * 32 + mt * 16 + l16) * ND + ks * 32 + quad * 8;
            qfh[mt][ks] = *(const f16x8*)(Qh + o);
            qfl[mt][ks] = *(const f16x8*)(Ql + o);
        }

    f32x4 O[2][4] = {};
    float dsum[2][4] = {};

    for (int kt = 0; kt < 8; kt++) {
        // S = Q K^T (split: qh*kh + ql*kh + qh*kl), 32 x 128 per wave
        f32x4 S[2][8] = {};
#pragma unroll
        for (int nt = 0; nt < 8; nt++) {
#pragma unroll
            for (int ks = 0; ks < 2; ks++) {
                size_t o = (size_t)(kt * 128 + nt * 16 + l16) * ND + ks * 32 + quad * 8;
                f16x8 bhf = *(const f16x8*)(Kh + o);
                f16x8 blf = *(const f16x8*)(Kl + o);
#pragma unroll
                for (int mt = 0; mt < 2; mt++) {
                    S[mt][nt] = __builtin_amdgcn_mfma_f32_16x16x32_f16(qfh[mt][ks], bhf, S[mt][nt], 0, 0, 0);
                    S[mt][nt] = __builtin_amdgcn_mfma_f32_16x16x32_f16(qfl[mt][ks], bhf, S[mt][nt], 0, 0, 0);
                    S[mt][nt] = __builtin_amdgcn_mfma_f32_16x16x32_f16(qfh[mt][ks], blf, S[mt][nt], 0, 0, 0);
                }
            }
        }
        // w = relu(a2*s^2 + b1*s + g0), fmaf-pinned; round to fp16 FIRST,
        // accumulate the rounded value into dsum (consistent normalization).
#pragma unroll
        for (int mt = 0; mt < 2; mt++) {
#pragma unroll
            for (int nt = 0; nt < 8; nt++) {
#pragma unroll
                for (int r = 0; r < 4; r++) {
                    float s = S[mt][nt][r];
                    float w = fmaxf(fmaf(fmaf(a2, s, b1), s, g0), 0.f);
                    _Float16 wh = (_Float16)w;
                    dsum[mt][r] += (float)wh;
                    sP[wv][(mt * 16 + quad * 4 + r) * 136 + nt * 16 + l16] = wh;
                }
            }
        }
        LDS_FENCE();  // P writes complete; cross-lane visible within wave
        // O += P * V : A = P (LDS), B = V^T (global, contiguous along kv index)
#pragma unroll
        for (int ks = 0; ks < 4; ks++) {
#pragma unroll
            for (int nt = 0; nt < 4; nt++) {
                f16x8 bfr = *(const f16x8*)(Vb + (size_t)(nt * 16 + l16) * NN + kt * 128 + ks * 32 + quad * 8);
#pragma unroll
                for (int mt = 0; mt < 2; mt++) {
                    f16x8 af = *(const f16x8*)(&sP[wv][(mt * 16 + l16) * 136 + ks * 32 + quad * 8]);
                    O[mt][nt] = __builtin_amdgcn_mfma_f32_16x16x32_f16(af, bfr, O[mt][nt], 0, 0, 0);
                }
            }
        }
        LDS_FENCE();  // P reads done before next iteration's writes
    }

    // denominator: reduce across the 16 lanes of each quad-group
#pragma unroll
    for (int mt = 0; mt < 2; mt++)
#pragma unroll
        for (int r = 0; r < 4; r++) {
            float v = dsum[mt][r];
            v += __shfl_xor(v, 1);
            v += __shfl_xor(v, 2);
            v += __shfl_xor(v, 4);
            v += __shfl_xor(v, 8);
            dsum[mt][r] = 1.0f / (v + 1e-6f);
        }

    // normalize + store fp32 to outh32[B,N,H*d]
    const int base_row = qt * 128 + wv * 32;
#pragma unroll
    for (int mt = 0; mt < 2; mt++) {
#pragma unroll
        for (int nt = 0; nt < 4; nt++) {
#pragma unroll
            for (int r = 0; r < 4; r++) {
                float v = O[mt][nt][r] * dsum[mt][r];
                int row = base_row + mt * 16 + quad * 4 + r;  // token n
                int col = h * ND + nt * 16 + l16;             // channel c
                outh32[((size_t)(b * NN + row)) * NC + col] = v;
            }
        }
    }
}

// ---------------- proj GEMM: out = outh32 * Wproj^T + b_proj, 3-term split ----------------
__global__ __launch_bounds__(256) void gemm_proj(
    const float* __restrict__ A,
    const _Float16* __restrict__ Bh, const _Float16* __restrict__ Bl,
    const float* __restrict__ bias, float* __restrict__ out)
{
    __shared__ __align__(16) _Float16 sAh[128 * 32];
    __shared__ __align__(16) _Float16 sAl[128 * 32];
    __shared__ __align__(16) _Float16 sBh[128 * 32];
    __shared__ __align__(16) _Float16 sBl[128 * 32];
    const int tid = threadIdx.x;
    const int lane = tid & 63, wv = tid >> 6;
    const int quad = lane >> 4, l16 = lane & 15;
    const int wm = (wv >> 1) * 64, wn = (wv & 1) * 64;
    const int m0 = blockIdx.x * 128, n0 = blockIdx.y * 128;

    f32x4 acc[4][4] = {};

    for (int k0 = 0; k0 < NC; k0 += 32) {
#pragma unroll
        for (int i = 0; i < 2; i++) {
            int c = tid + i * 256;
            int r = c >> 2, kc = c & 3;
            const float4* pa = (const float4*)(A + (size_t)(m0 + r) * NC + k0 + kc * 8);
            float4 v0 = pa[0], v1 = pa[1];
            f16x8 hi8, lo8;
            hi8[0] = (_Float16)v0.x; lo8[0] = (_Float16)(v0.x - (float)hi8[0]);
            hi8[1] = (_Float16)v0.y; lo8[1] = (_Float16)(v0.y - (float)hi8[1]);
            hi8[2] = (_Float16)v0.z; lo8[2] = (_Float16)(v0.z - (float)hi8[2]);
            hi8[3] = (_Float16)v0.w; lo8[3] = (_Float16)(v0.w - (float)hi8[3]);
            hi8[4] = (_Float16)v1.x; lo8[4] = (_Float16)(v1.x - (float)hi8[4]);
            hi8[5] = (_Float16)v1.y; lo8[5] = (_Float16)(v1.y - (float)hi8[5]);
            hi8[6] = (_Float16)v1.z; lo8[6] = (_Float16)(v1.z - (float)hi8[6]);
            hi8[7] = (_Float16)v1.w; lo8[7] = (_Float16)(v1.w - (float)hi8[7]);
            *(f16x8*)(sAh + c * 8) = hi8;
            *(f16x8*)(sAl + c * 8) = lo8;
            size_t goB = (size_t)(n0 + r) * NC + k0 + kc * 8;
            async16(Bh + goB, sBh + c * 8);
            async16(Bl + goB, sBl + c * 8);
        }
        __syncthreads();
        f16x8 ah[4], al[4], bh[4], bl[4];
#pragma unroll
        for (int t = 0; t < 4; t++) {
            ah[t] = *(const f16x8*)(sAh + (wm + t * 16 + l16) * 32 + quad * 8);
            al[t] = *(const f16x8*)(sAl + (wm + t * 16 + l16) * 32 + quad * 8);
            bh[t] = *(const f16x8*)(sBh + (wn + t * 16 + l16) * 32 + quad * 8);
            bl[t] = *(const f16x8*)(sBl + (wn + t * 16 + l16) * 32 + quad * 8);
        }
#pragma unroll
        for (int i = 0; i < 4; i++)
#pragma unroll
            for (int j = 0; j < 4; j++) {
                acc[i][j] = __builtin_amdgcn_mfma_f32_16x16x32_f16(ah[i], bh[j], acc[i][j], 0, 0, 0);
                acc[i][j] = __builtin_amdgcn_mfma_f32_16x16x32_f16(al[i], bh[j], acc[i][j], 0, 0, 0);
                acc[i][j] = __builtin_amdgcn_mfma_f32_16x16x32_f16(ah[i], bl[j], acc[i][j], 0, 0, 0);
            }
        __syncthreads();
    }

#pragma unroll
    for (int i = 0; i < 4; i++) {
#pragma unroll
        for (int j = 0; j < 4; j++) {
#pragma unroll
            for (int r = 0; r < 4; r++) {
                int row = m0 + wm + i * 16 + quad * 4 + r;
                int col = n0 + wn + j * 16 + l16;
                out[(size_t)row * NC + col] = acc[i][j][r] + bias[col];
            }
        }
    }
}

// ---------------- launch ----------------
extern "C" void kernel_launch(void* const* d_in, const int* in_sizes, int n_in,
                              void* d_out, int out_size, void* d_ws, size_t ws_size,
                              hipStream_t stream) {
    const float* x      = (const float*)d_in[0];
    const float* w_qkv  = (const float*)d_in[1];
    const float* w_proj = (const float*)d_in[2];
    const float* b_proj = (const float*)d_in[3];
    const float* alpha  = (const float*)d_in[4];
    const float* beta   = (const float*)d_in[5];
    const float* gamma  = (const float*)d_in[6];
    float* out = (float*)d_out;

    char* ws = (char*)d_ws;
    float*    outh32 = (float*)(ws + 0);               // 25,165,824 B
    _Float16* wqkvh  = (_Float16*)(ws + 25165824);     //  3,538,944 B
    _Float16* wqkvl  = (_Float16*)(ws + 28704768);     //  3,538,944 B
    _Float16* wprojh = (_Float16*)(ws + 32243712);     //  1,179,648 B
    _Float16* wprojl = (_Float16*)(ws + 33423360);     //  1,179,648 B
    _Float16* qh     = (_Float16*)(ws + 34603008);     // 12,582,912 B
    _Float16* ql     = (_Float16*)(ws + 47185920);
    _Float16* kh     = (_Float16*)(ws + 59768832);
    _Float16* kl     = (_Float16*)(ws + 72351744);
    _Float16* vt16   = (_Float16*)(ws + 84934656);     // ends 97,517,568 B

    cvt_split_f32<<<1728, 256, 0, stream>>>(w_qkv, wqkvh, wqkvl, 442368);
    cvt_split_f32<<<576, 256, 0, stream>>>(w_proj, wprojh, wprojl, 147456);

    gemm_qkv<<<dim3(64, 18), 256, 0, stream>>>(x, wqkvh, wqkvl, qh, ql, kh, kl, vt16);
    attn_kernel<<<dim3(8, 96), 256, 0, stream>>>(qh, ql, kh, kl, vt16, outh32, alpha, beta, gamma);
    gemm_proj<<<dim3(64, 6), 256, 0, stream>>>(outh32, wprojh, wprojl, b_proj, out);
}

// Round 5
// 306.831 us; speedup vs baseline: 1.5089x; 1.5089x over previous
//
#include <hip/hip_runtime.h>

// L2Q attention, fp16-MFMA, hi/lo split on q/k path AND proj GEMM.
// B=8, N=1024, C=768, H=12, d=64, 3C=2304, M=B*N=8192.
// R5: attn restructured — S^T=K·Q^T with swizzled K-row tiles so PV B-frags
//     are direct register re-packs (no LDS P round-trip, no fences);
//     K/V staged cooperatively in LDS via global_load_lds with XOR chunk
//     swizzle (conflict-free reads); qkv GEMM back to pre-split async16.

typedef _Float16 f16x8 __attribute__((ext_vector_type(8)));
typedef _Float16 f16x4 __attribute__((ext_vector_type(4)));
typedef float f32x4 __attribute__((ext_vector_type(4)));

#define NB 8
#define NN 1024
#define NC 768
#define NH 12
#define ND 64
#define TC 2304
#define NM 8192

__device__ __forceinline__ void async16(const void* g, void* l) {
    __builtin_amdgcn_global_load_lds(
        (const __attribute__((address_space(1))) void*)g,
        (__attribute__((address_space(3))) void*)l, 16, 0, 0);
}

// ---------------- fp32 -> fp16 hi/lo split ----------------
__global__ void cvt_split_f32(const float* __restrict__ s, _Float16* __restrict__ hi,
                              _Float16* __restrict__ lo, int n4) {
    int i = blockIdx.x * 256 + threadIdx.x;
    if (i < n4) {
        float4 v = ((const float4*)s)[i];
        f16x4 h, l;
        h[0] = (_Float16)v.x; l[0] = (_Float16)(v.x - (float)h[0]);
        h[1] = (_Float16)v.y; l[1] = (_Float16)(v.y - (float)h[1]);
        h[2] = (_Float16)v.z; l[2] = (_Float16)(v.z - (float)h[2]);
        h[3] = (_Float16)v.w; l[3] = (_Float16)(v.w - (float)h[3]);
        ((f16x4*)hi)[i] = h;
        ((f16x4*)lo)[i] = l;
    }
}

// ---------------- qkv GEMM: C[8192,2304] = X * Wqkv^T ----------------
// q/k columns: 3-term split (ah*bh + al*bh + ah*bl). v columns: 1-term.
// All tiles staged via global_load_lds(16B).
__global__ __launch_bounds__(256) void gemm_qkv(
    const _Float16* __restrict__ Ah, const _Float16* __restrict__ Al,
    const _Float16* __restrict__ Bh, const _Float16* __restrict__ Bl,
    _Float16* __restrict__ qh, _Float16* __restrict__ ql,
    _Float16* __restrict__ kh, _Float16* __restrict__ kl,
    _Float16* __restrict__ vt16)
{
    __shared__ __align__(16) _Float16 sAh[128 * 32];
    __shared__ __align__(16) _Float16 sAl[128 * 32];
    __shared__ __align__(16) _Float16 sBh[128 * 32];
    __shared__ __align__(16) _Float16 sBl[128 * 32];
    const int tid = threadIdx.x;
    const int lane = tid & 63, wv = tid >> 6;
    const int quad = lane >> 4, l16 = lane & 15;
    const int wm = (wv >> 1) * 64, wn = (wv & 1) * 64;
    const int m0 = blockIdx.x * 128, n0 = blockIdx.y * 128;
    const bool is_v = (n0 >= 2 * NC);   // v third: 1-term suffices

    f32x4 acc[4][4] = {};

    for (int k0 = 0; k0 < NC; k0 += 32) {
#pragma unroll
        for (int i = 0; i < 2; i++) {
            int c = tid + i * 256;       // chunk 0..511 (lane-contiguous 16B)
            int r = c >> 2, kc = c & 3;
            size_t goA = (size_t)(m0 + r) * NC + k0 + kc * 8;
            size_t goB = (size_t)(n0 + r) * NC + k0 + kc * 8;
            async16(Ah + goA, sAh + c * 8);
            async16(Bh + goB, sBh + c * 8);
            if (!is_v) {
                async16(Al + goA, sAl + c * 8);
                async16(Bl + goB, sBl + c * 8);
            }
        }
        __syncthreads();
        f16x8 ah[4], bh[4];
#pragma unroll
        for (int t = 0; t < 4; t++) {
            ah[t] = *(const f16x8*)(sAh + (wm + t * 16 + l16) * 32 + quad * 8);
            bh[t] = *(const f16x8*)(sBh + (wn + t * 16 + l16) * 32 + quad * 8);
        }
        if (!is_v) {
            f16x8 al[4], bl[4];
#pragma unroll
            for (int t = 0; t < 4; t++) {
                al[t] = *(const f16x8*)(sAl + (wm + t * 16 + l16) * 32 + quad * 8);
                bl[t] = *(const f16x8*)(sBl + (wn + t * 16 + l16) * 32 + quad * 8);
            }
#pragma unroll
            for (int i = 0; i < 4; i++)
#pragma unroll
                for (int j = 0; j < 4; j++) {
                    acc[i][j] = __builtin_amdgcn_mfma_f32_16x16x32_f16(ah[i], bh[j], acc[i][j], 0, 0, 0);
                    acc[i][j] = __builtin_amdgcn_mfma_f32_16x16x32_f16(al[i], bh[j], acc[i][j], 0, 0, 0);
                    acc[i][j] = __builtin_amdgcn_mfma_f32_16x16x32_f16(ah[i], bl[j], acc[i][j], 0, 0, 0);
                }
        } else {
#pragma unroll
            for (int i = 0; i < 4; i++)
#pragma unroll
                for (int j = 0; j < 4; j++)
                    acc[i][j] = __builtin_amdgcn_mfma_f32_16x16x32_f16(ah[i], bh[j], acc[i][j], 0, 0, 0);
        }
        __syncthreads();
    }

    // epilogue: q,k as hi/lo pairs [B,H,N,d]; v^T fp16 [B,H,d,N]
#pragma unroll
    for (int i = 0; i < 4; i++) {
#pragma unroll
        for (int j = 0; j < 4; j++) {
#pragma unroll
            for (int r = 0; r < 4; r++) {
                int row = m0 + wm + i * 16 + quad * 4 + r;
                int col = n0 + wn + j * 16 + l16;
                float fv = acc[i][j][r];
                int b = row >> 10, nr = row & 1023;
                int which = col / NC;
                int w2 = col - which * NC;
                int h = w2 >> 6, dd = w2 & 63;
                int bhd = b * NH + h;
                size_t idx = ((size_t)(bhd * NN + nr)) * ND + dd;
                if (which == 0) {
                    _Float16 hv = (_Float16)fv;
                    qh[idx] = hv;
                    ql[idx] = (_Float16)(fv - (float)hv);
                } else if (which == 1) {
                    _Float16 hv = (_Float16)fv;
                    kh[idx] = hv;
                    kl[idx] = (_Float16)(fv - (float)hv);
                } else {
                    vt16[((size_t)(bhd * ND + dd)) * NN + nr] = (_Float16)fv;
                }
            }
        }
    }
}

// ---------------- fused quadratic-ReLU attention ----------------
// grid (8 q-tiles, 96 bh), 256 threads = 4 waves; wave handles 32 q-rows.
// S^T = K*Q^T with swizzled K-row tiles: tile (ks2,T) lane i covers kv row
// ks2*32 + 8*(i>>2) + 4T + (i&3). Then S^T acc (quad,l16,reg r) holds
// P^T[ks2*32+8*quad+4T+r][q=l16] == element (4T|r) of the PV B-fragment on
// the SAME lane -> register re-pack, no LDS transpose, no fences.
__global__ __launch_bounds__(256) void attn_kernel(
    const _Float16* __restrict__ qhp, const _Float16* __restrict__ qlp,
    const _Float16* __restrict__ khp, const _Float16* __restrict__ klp,
    const _Float16* __restrict__ vt16, float* __restrict__ outh32,
    const float* __restrict__ alpha, const float* __restrict__ beta,
    const float* __restrict__ gamma)
{
    const int qt = blockIdx.x, bh = blockIdx.y;
    const int b = bh / NH, h = bh - b * NH;
    const int tid = threadIdx.x, lane = tid & 63, wv = tid >> 6;
    const int quad = lane >> 4, l16 = lane & 15;
    const float a2 = alpha[h] * 0.015625f;   // alpha * SCALE^2
    const float b1 = beta[h] * 0.125f;       // beta * SCALE
    const float g0 = gamma[h];

    // K/V tiles for one kt step (128 kv rows), XOR-chunk-swizzled.
    __shared__ __align__(16) _Float16 sKh[128 * 64];  // 16 KB
    __shared__ __align__(16) _Float16 sKl[128 * 64];  // 16 KB
    __shared__ __align__(16) _Float16 sVt[64 * 128];  // 16 KB

    const size_t qoff = ((size_t)(bh * NN + qt * 128)) * ND;
    const _Float16* Qh = qhp + qoff;
    const _Float16* Ql = qlp + qoff;
    const _Float16* Kh = khp + (size_t)bh * NN * ND;
    const _Float16* Kl = klp + (size_t)bh * NN * ND;
    const _Float16* Vb = vt16 + (size_t)bh * ND * NN;

    // Q fragments (hi and lo): 2 m-tiles x 2 d-chunks (used as MFMA B-operand)
    f16x8 qfh[2][2], qfl[2][2];
#pragma unroll
    for (int mt = 0; mt < 2; mt++)
#pragma unroll
        for (int ksd = 0; ksd < 2; ksd++) {
            size_t o = (size_t)(wv * 32 + mt * 16 + l16) * ND + ksd * 32 + quad * 8;
            qfh[mt][ksd] = *(const f16x8*)(Qh + o);
            qfl[mt][ksd] = *(const f16x8*)(Ql + o);
        }

    f32x4 O[4][2] = {};        // [dt][mt]: O[q=mt*16+l16][d=dt*16+quad*4+r]
    float dsum[2] = {0.f, 0.f};

    for (int kt = 0; kt < 8; kt++) {
        // ---- stage K(hi,lo) and V^T tiles, source-swizzled ----
#pragma unroll
        for (int i = 0; i < 4; i++) {
            int L = tid + i * 256;             // chunk 0..1023
            int row = L >> 3, pos = L & 7;     // K: [128 rows][8 chunks]
            int c = pos ^ ((row & 7) ^ (((row >> 3) & 3) << 1));
            size_t src = (size_t)(kt * 128 + row) * ND + c * 8;
            async16(Kh + src, sKh + L * 8);
            async16(Kl + src, sKl + L * 8);
        }
#pragma unroll
        for (int i = 0; i < 4; i++) {
            int L = tid + i * 256;             // chunk 0..1023
            int row = L >> 4, pos = L & 15;    // V^T: [64 d][16 chunks]
            int c = pos ^ (row & 15);
            async16(Vb + (size_t)row * NN + kt * 128 + c * 8, sVt + L * 8);
        }
        __syncthreads();   // vmcnt drained by compiler before barrier

        // ---- S^T tiles + poly -> PV B-fragments (registers only) ----
        f16x8 bfrag[2][4];
#pragma unroll
        for (int ks2 = 0; ks2 < 4; ks2++) {
#pragma unroll
            for (int T = 0; T < 2; T++) {
                int row = ks2 * 32 + 8 * (l16 >> 2) + 4 * T + (l16 & 3);
                int swz = (row & 7) ^ (((row >> 3) & 3) << 1);
                f16x8 ah[2], al[2];
#pragma unroll
                for (int ksd = 0; ksd < 2; ksd++) {
                    int cc = (ksd * 4 + quad) ^ swz;
                    int addr = row * 64 + cc * 8;
                    ah[ksd] = *(const f16x8*)(sKh + addr);
                    al[ksd] = *(const f16x8*)(sKl + addr);
                }
#pragma unroll
                for (int mt = 0; mt < 2; mt++) {
                    f32x4 S = {};
#pragma unroll
                    for (int ksd = 0; ksd < 2; ksd++) {
                        S = __builtin_amdgcn_mfma_f32_16x16x32_f16(ah[ksd], qfh[mt][ksd], S, 0, 0, 0);
                        S = __builtin_amdgcn_mfma_f32_16x16x32_f16(al[ksd], qfh[mt][ksd], S, 0, 0, 0);
                        S = __builtin_amdgcn_mfma_f32_16x16x32_f16(ah[ksd], qfl[mt][ksd], S, 0, 0, 0);
                    }
#pragma unroll
                    for (int r = 0; r < 4; r++) {
                        float s = S[r];
                        float w = fmaxf(fmaf(fmaf(a2, s, b1), s, g0), 0.f);
                        _Float16 wh = (_Float16)w;
                        dsum[mt] += (float)wh;
                        bfrag[mt][ks2][(T << 2) | r] = wh;
                    }
                }
            }
        }

        // ---- O += V^T x P^T (A = V^T frag from LDS, B = bfrag registers) ----
#pragma unroll
        for (int ks2 = 0; ks2 < 4; ks2++) {
#pragma unroll
            for (int dt = 0; dt < 4; dt++) {
                int cc = (ks2 * 4 + quad) ^ l16;
                f16x8 vf = *(const f16x8*)(sVt + (dt * 16 + l16) * 128 + cc * 8);
#pragma unroll
                for (int mt = 0; mt < 2; mt++)
                    O[dt][mt] = __builtin_amdgcn_mfma_f32_16x16x32_f16(vf, bfrag[mt][ks2], O[dt][mt], 0, 0, 0);
            }
        }
        __syncthreads();   // compute done before next stage overwrites
    }

    // denominator: per-lane partial covers kv rows 8*quad+... -> reduce across quads
    float rinv[2];
#pragma unroll
    for (int mt = 0; mt < 2; mt++) {
        float v = dsum[mt];
        v += __shfl_xor(v, 16);
        v += __shfl_xor(v, 32);
        rinv[mt] = 1.0f / (v + 1e-6f);
    }

    // normalize + store fp32 to outh32[B,N,H*d], float4 per (dt,mt)
    const int base_row = qt * 128 + wv * 32;
#pragma unroll
    for (int dt = 0; dt < 4; dt++) {
#pragma unroll
        for (int mt = 0; mt < 2; mt++) {
            float4 o4;
            o4.x = O[dt][mt][0] * rinv[mt];
            o4.y = O[dt][mt][1] * rinv[mt];
            o4.z = O[dt][mt][2] * rinv[mt];
            o4.w = O[dt][mt][3] * rinv[mt];
            int row = base_row + mt * 16 + l16;                 // token n
            int col = h * ND + dt * 16 + quad * 4;              // channel c
            *(float4*)(outh32 + (size_t)(b * NN + row) * NC + col) = o4;
        }
    }
}

// ---------------- proj GEMM: out = outh32 * Wproj^T + b_proj, 3-term split ----------------
__global__ __launch_bounds__(256) void gemm_proj(
    const float* __restrict__ A,
    const _Float16* __restrict__ Bh, const _Float16* __restrict__ Bl,
    const float* __restrict__ bias, float* __restrict__ out)
{
    __shared__ __align__(16) _Float16 sAh[128 * 32];
    __shared__ __align__(16) _Float16 sAl[128 * 32];
    __shared__ __align__(16) _Float16 sBh[128 * 32];
    __shared__ __align__(16) _Float16 sBl[128 * 32];
    const int tid = threadIdx.x;
    const int lane = tid & 63, wv = tid >> 6;
    const int quad = lane >> 4, l16 = lane & 15;
    const int wm = (wv >> 1) * 64, wn = (wv & 1) * 64;
    const int m0 = blockIdx.x * 128, n0 = blockIdx.y * 128;

    f32x4 acc[4][4] = {};

    for (int k0 = 0; k0 < NC; k0 += 32) {
#pragma unroll
        for (int i = 0; i < 2; i++) {
            int c = tid + i * 256;
            int r = c >> 2, kc = c & 3;
            const float4* pa = (const float4*)(A + (size_t)(m0 + r) * NC + k0 + kc * 8);
            float4 v0 = pa[0], v1 = pa[1];
            f16x8 hi8, lo8;
            hi8[0] = (_Float16)v0.x; lo8[0] = (_Float16)(v0.x - (float)hi8[0]);
            hi8[1] = (_Float16)v0.y; lo8[1] = (_Float16)(v0.y - (float)hi8[1]);
            hi8[2] = (_Float16)v0.z; lo8[2] = (_Float16)(v0.z - (float)hi8[2]);
            hi8[3] = (_Float16)v0.w; lo8[3] = (_Float16)(v0.w - (float)hi8[3]);
            hi8[4] = (_Float16)v1.x; lo8[4] = (_Float16)(v1.x - (float)hi8[4]);
            hi8[5] = (_Float16)v1.y; lo8[5] = (_Float16)(v1.y - (float)hi8[5]);
            hi8[6] = (_Float16)v1.z; lo8[6] = (_Float16)(v1.z - (float)hi8[6]);
            hi8[7] = (_Float16)v1.w; lo8[7] = (_Float16)(v1.w - (float)hi8[7]);
            *(f16x8*)(sAh + c * 8) = hi8;
            *(f16x8*)(sAl + c * 8) = lo8;
            size_t goB = (size_t)(n0 + r) * NC + k0 + kc * 8;
            async16(Bh + goB, sBh + c * 8);
            async16(Bl + goB, sBl + c * 8);
        }
        __syncthreads();
        f16x8 ah[4], al[4], bh[4], bl[4];
#pragma unroll
        for (int t = 0; t < 4; t++) {
            ah[t] = *(const f16x8*)(sAh + (wm + t * 16 + l16) * 32 + quad * 8);
            al[t] = *(const f16x8*)(sAl + (wm + t * 16 + l16) * 32 + quad * 8);
            bh[t] = *(const f16x8*)(sBh + (wn + t * 16 + l16) * 32 + quad * 8);
            bl[t] = *(const f16x8*)(sBl + (wn + t * 16 + l16) * 32 + quad * 8);
        }
#pragma unroll
        for (int i = 0; i < 4; i++)
#pragma unroll
            for (int j = 0; j < 4; j++) {
                acc[i][j] = __builtin_amdgcn_mfma_f32_16x16x32_f16(ah[i], bh[j], acc[i][j], 0, 0, 0);
                acc[i][j] = __builtin_amdgcn_mfma_f32_16x16x32_f16(al[i], bh[j], acc[i][j], 0, 0, 0);
                acc[i][j] = __builtin_amdgcn_mfma_f32_16x16x32_f16(ah[i], bl[j], acc[i][j], 0, 0, 0);
            }
        __syncthreads();
    }

#pragma unroll
    for (int i = 0; i < 4; i++) {
#pragma unroll
        for (int j = 0; j < 4; j++) {
#pragma unroll
            for (int r = 0; r < 4; r++) {
                int row = m0 + wm + i * 16 + quad * 4 + r;
                int col = n0 + wn + j * 16 + l16;
                out[(size_t)row * NC + col] = acc[i][j][r] + bias[col];
            }
        }
    }
}

// ---------------- launch ----------------
extern "C" void kernel_launch(void* const* d_in, const int* in_sizes, int n_in,
                              void* d_out, int out_size, void* d_ws, size_t ws_size,
                              hipStream_t stream) {
    const float* x      = (const float*)d_in[0];
    const float* w_qkv  = (const float*)d_in[1];
    const float* w_proj = (const float*)d_in[2];
    const float* b_proj = (const float*)d_in[3];
    const float* alpha  = (const float*)d_in[4];
    const float* beta   = (const float*)d_in[5];
    const float* gamma  = (const float*)d_in[6];
    float* out = (float*)d_out;

    char* ws = (char*)d_ws;
    _Float16* xh     = (_Float16*)(ws + 0);            // 12,582,912 B (dead after gemm_qkv)
    _Float16* xl     = (_Float16*)(ws + 12582912);     // 12,582,912 B (dead after gemm_qkv)
    float*    outh32 = (float*)(ws + 0);               // 25,165,824 B (overlays xh/xl)
    _Float16* wqkvh  = (_Float16*)(ws + 25165824);     //  3,538,944 B
    _Float16* wqkvl  = (_Float16*)(ws + 28704768);     //  3,538,944 B
    _Float16* wprojh = (_Float16*)(ws + 32243712);     //  1,179,648 B
    _Float16* wprojl = (_Float16*)(ws + 33423360);     //  1,179,648 B
    _Float16* qh     = (_Float16*)(ws + 34603008);     // 12,582,912 B
    _Float16* ql     = (_Float16*)(ws + 47185920);
    _Float16* kh     = (_Float16*)(ws + 59768832);
    _Float16* kl     = (_Float16*)(ws + 72351744);
    _Float16* vt16   = (_Float16*)(ws + 84934656);     // ends 97,517,568 B

    cvt_split_f32<<<6144, 256, 0, stream>>>(x, xh, xl, 1572864);
    cvt_split_f32<<<1728, 256, 0, stream>>>(w_qkv, wqkvh, wqkvl, 442368);
    cvt_split_f32<<<576, 256, 0, stream>>>(w_proj, wprojh, wprojl, 147456);

    gemm_qkv<<<dim3(64, 18), 256, 0, stream>>>(xh, xl, wqkvh, wqkvl, qh, ql, kh, kl, vt16);
    attn_kernel<<<dim3(8, 96), 256, 0, stream>>>(qh, ql, kh, kl, vt16, outh32, alpha, beta, gamma);
    gemm_proj<<<dim3(64, 6), 256, 0, stream>>>(outh32, wprojh, wprojl, b_proj, out);
}

// Round 6
// 300.476 us; speedup vs baseline: 1.5408x; 1.0211x over previous
//
#include <hip/hip_runtime.h>

// L2Q attention, fp16-MFMA, hi/lo split on q/k path AND proj GEMM.
// B=8, N=1024, C=768, H=12, d=64, 3C=2304, M=B*N=8192.
// R6: attn QK restructured for 8-way MFMA ILP (S[2][4] batched chains);
//     attn K/V LDS in fragment-major layout (conflict-free b128 reads);
//     GEMM split terms reordered term-major (16-way ILP, bit-identical).

typedef _Float16 f16x8 __attribute__((ext_vector_type(8)));
typedef _Float16 f16x4 __attribute__((ext_vector_type(4)));
typedef float f32x4 __attribute__((ext_vector_type(4)));

#define NB 8
#define NN 1024
#define NC 768
#define NH 12
#define ND 64
#define TC 2304
#define NM 8192

__device__ __forceinline__ void async16(const void* g, void* l) {
    __builtin_amdgcn_global_load_lds(
        (const __attribute__((address_space(1))) void*)g,
        (__attribute__((address_space(3))) void*)l, 16, 0, 0);
}

// ---------------- fp32 -> fp16 hi/lo split ----------------
__global__ void cvt_split_f32(const float* __restrict__ s, _Float16* __restrict__ hi,
                              _Float16* __restrict__ lo, int n4) {
    int i = blockIdx.x * 256 + threadIdx.x;
    if (i < n4) {
        float4 v = ((const float4*)s)[i];
        f16x4 h, l;
        h[0] = (_Float16)v.x; l[0] = (_Float16)(v.x - (float)h[0]);
        h[1] = (_Float16)v.y; l[1] = (_Float16)(v.y - (float)h[1]);
        h[2] = (_Float16)v.z; l[2] = (_Float16)(v.z - (float)h[2]);
        h[3] = (_Float16)v.w; l[3] = (_Float16)(v.w - (float)h[3]);
        ((f16x4*)hi)[i] = h;
        ((f16x4*)lo)[i] = l;
    }
}

// ---------------- qkv GEMM: C[8192,2304] = X * Wqkv^T ----------------
// q/k columns: 3-term split, term-major (hh x16, lh x16, hl x16 - 16-way ILP).
__global__ __launch_bounds__(256) void gemm_qkv(
    const _Float16* __restrict__ Ah, const _Float16* __restrict__ Al,
    const _Float16* __restrict__ Bh, const _Float16* __restrict__ Bl,
    _Float16* __restrict__ qh, _Float16* __restrict__ ql,
    _Float16* __restrict__ kh, _Float16* __restrict__ kl,
    _Float16* __restrict__ vt16)
{
    __shared__ __align__(16) _Float16 sAh[128 * 32];
    __shared__ __align__(16) _Float16 sAl[128 * 32];
    __shared__ __align__(16) _Float16 sBh[128 * 32];
    __shared__ __align__(16) _Float16 sBl[128 * 32];
    const int tid = threadIdx.x;
    const int lane = tid & 63, wv = tid >> 6;
    const int quad = lane >> 4, l16 = lane & 15;
    const int wm = (wv >> 1) * 64, wn = (wv & 1) * 64;
    const int m0 = blockIdx.x * 128, n0 = blockIdx.y * 128;
    const bool is_v = (n0 >= 2 * NC);

    f32x4 acc[4][4] = {};

    for (int k0 = 0; k0 < NC; k0 += 32) {
#pragma unroll
        for (int i = 0; i < 2; i++) {
            int c = tid + i * 256;
            int r = c >> 2, kc = c & 3;
            size_t goA = (size_t)(m0 + r) * NC + k0 + kc * 8;
            size_t goB = (size_t)(n0 + r) * NC + k0 + kc * 8;
            async16(Ah + goA, sAh + c * 8);
            async16(Bh + goB, sBh + c * 8);
            if (!is_v) {
                async16(Al + goA, sAl + c * 8);
                async16(Bl + goB, sBl + c * 8);
            }
        }
        __syncthreads();
        f16x8 ah[4], bh[4];
#pragma unroll
        for (int t = 0; t < 4; t++) {
            ah[t] = *(const f16x8*)(sAh + (wm + t * 16 + l16) * 32 + quad * 8);
            bh[t] = *(const f16x8*)(sBh + (wn + t * 16 + l16) * 32 + quad * 8);
        }
        // term 1: hh (16 independent MFMAs)
#pragma unroll
        for (int i = 0; i < 4; i++)
#pragma unroll
            for (int j = 0; j < 4; j++)
                acc[i][j] = __builtin_amdgcn_mfma_f32_16x16x32_f16(ah[i], bh[j], acc[i][j], 0, 0, 0);
        if (!is_v) {
            f16x8 al[4], bl[4];
#pragma unroll
            for (int t = 0; t < 4; t++) {
                al[t] = *(const f16x8*)(sAl + (wm + t * 16 + l16) * 32 + quad * 8);
                bl[t] = *(const f16x8*)(sBl + (wn + t * 16 + l16) * 32 + quad * 8);
            }
            // term 2: lh
#pragma unroll
            for (int i = 0; i < 4; i++)
#pragma unroll
                for (int j = 0; j < 4; j++)
                    acc[i][j] = __builtin_amdgcn_mfma_f32_16x16x32_f16(al[i], bh[j], acc[i][j], 0, 0, 0);
            // term 3: hl
#pragma unroll
            for (int i = 0; i < 4; i++)
#pragma unroll
                for (int j = 0; j < 4; j++)
                    acc[i][j] = __builtin_amdgcn_mfma_f32_16x16x32_f16(ah[i], bl[j], acc[i][j], 0, 0, 0);
        }
        __syncthreads();
    }

    // epilogue: q,k as hi/lo pairs [B,H,N,d]; v^T fp16 [B,H,d,N]
#pragma unroll
    for (int i = 0; i < 4; i++) {
#pragma unroll
        for (int j = 0; j < 4; j++) {
#pragma unroll
            for (int r = 0; r < 4; r++) {
                int row = m0 + wm + i * 16 + quad * 4 + r;
                int col = n0 + wn + j * 16 + l16;
                float fv = acc[i][j][r];
                int b = row >> 10, nr = row & 1023;
                int which = col / NC;
                int w2 = col - which * NC;
                int h = w2 >> 6, dd = w2 & 63;
                int bhd = b * NH + h;
                size_t idx = ((size_t)(bhd * NN + nr)) * ND + dd;
                if (which == 0) {
                    _Float16 hv = (_Float16)fv;
                    qh[idx] = hv;
                    ql[idx] = (_Float16)(fv - (float)hv);
                } else if (which == 1) {
                    _Float16 hv = (_Float16)fv;
                    kh[idx] = hv;
                    kl[idx] = (_Float16)(fv - (float)hv);
                } else {
                    vt16[((size_t)(bhd * ND + dd)) * NN + nr] = (_Float16)fv;
                }
            }
        }
    }
}

// ---------------- fused quadratic-ReLU attention ----------------
// grid (8 q-tiles, 96 bh), 256 threads = 4 waves; wave handles 32 q-rows.
// S^T = K*Q^T; K-row assignment per fragment (ks2,T): lane i covers kv row
// ks2*32 + 8*(i>>2) + 4T + (i&3), so S^T acc (quad,l16,reg r) IS element
// (4T|r) of the PV B-fragment on the same lane (register re-pack).
// K/V LDS tiles in FRAGMENT-MAJOR layout: each 64-lane fragment read is 64
// consecutive 16B chunks -> conflict-free; staging permutes source only
// (async16 dest stays lane-linear).
__global__ __launch_bounds__(256) void attn_kernel(
    const _Float16* __restrict__ qhp, const _Float16* __restrict__ qlp,
    const _Float16* __restrict__ khp, const _Float16* __restrict__ klp,
    const _Float16* __restrict__ vt16, float* __restrict__ outh32,
    const float* __restrict__ alpha, const float* __restrict__ beta,
    const float* __restrict__ gamma)
{
    const int qt = blockIdx.x, bh = blockIdx.y;
    const int b = bh / NH, h = bh - b * NH;
    const int tid = threadIdx.x, lane = tid & 63, wv = tid >> 6;
    const int quad = lane >> 4, l16 = lane & 15;
    const float a2 = alpha[h] * 0.015625f;   // alpha * SCALE^2
    const float b1 = beta[h] * 0.125f;       // beta * SCALE
    const float g0 = gamma[h];

    __shared__ __align__(16) _Float16 sKh[128 * 64];  // 16 KB, fragment-major
    __shared__ __align__(16) _Float16 sKl[128 * 64];  // 16 KB, fragment-major
    __shared__ __align__(16) _Float16 sVt[64 * 128];  // 16 KB, fragment-major

    const size_t qoff = ((size_t)(bh * NN + qt * 128)) * ND;
    const _Float16* Qh = qhp + qoff;
    const _Float16* Ql = qlp + qoff;
    const _Float16* Kh = khp + (size_t)bh * NN * ND;
    const _Float16* Kl = klp + (size_t)bh * NN * ND;
    const _Float16* Vb = vt16 + (size_t)bh * ND * NN;

    // Q fragments (hi and lo): 2 m-tiles x 2 d-chunks (MFMA B-operand)
    f16x8 qfh[2][2], qfl[2][2];
#pragma unroll
    for (int mt = 0; mt < 2; mt++)
#pragma unroll
        for (int ksd = 0; ksd < 2; ksd++) {
            size_t o = (size_t)(wv * 32 + mt * 16 + l16) * ND + ksd * 32 + quad * 8;
            qfh[mt][ksd] = *(const f16x8*)(Qh + o);
            qfl[mt][ksd] = *(const f16x8*)(Ql + o);
        }

    f32x4 O[4][2] = {};        // [dt][mt]
    float dsum[2] = {0.f, 0.f};

    for (int kt = 0; kt < 8; kt++) {
        // ---- stage K hi/lo, fragment-major: frag f=(ks2,T,ksd), chunk
        // P = f*64 + q*16 + (a*4+b) holds K[row=ks2*32+8a+4T+b][k=(ksd*4+q)*8..]
#pragma unroll
        for (int i = 0; i < 4; i++) {
            int P = tid + i * 256;
            int f = P >> 6, q = (P >> 4) & 3, a = (P >> 2) & 3, bb = P & 3;
            int ks2 = f >> 2, T = (f >> 1) & 1, ksd = f & 1;
            int row = ks2 * 32 + 8 * a + 4 * T + bb;
            size_t src = (size_t)(kt * 128 + row) * ND + (ksd * 4 + q) * 8;
            async16(Kh + src, sKh + P * 8);
            async16(Kl + src, sKl + P * 8);
        }
        // ---- stage V^T, fragment-major: frag f=(ks2,dt), chunk
        // P = f*64 + q*16 + l holds V^T[d=dt*16+l][kv=kt*128+(ks2*4+q)*8..]
#pragma unroll
        for (int i = 0; i < 4; i++) {
            int P = tid + i * 256;
            int f = P >> 6, q = (P >> 4) & 3, l = P & 15;
            int ks2 = f >> 2, dt = f & 3;
            async16(Vb + (size_t)(dt * 16 + l) * NN + kt * 128 + (ks2 * 4 + q) * 8,
                    sVt + P * 8);
        }
        __syncthreads();

        // ---- QK^T: 8 concurrent S chains (mt x ks2), T-major phases ----
        f16x8 bfrag[2][4];
#pragma unroll
        for (int T = 0; T < 2; T++) {
            f32x4 S[2][4] = {};
#pragma unroll
            for (int ks2 = 0; ks2 < 4; ks2++) {
#pragma unroll
                for (int ksd = 0; ksd < 2; ksd++) {
                    int addr = (((ks2 * 4 + T * 2 + ksd) * 64) + quad * 16 + l16) * 8;
                    f16x8 ah = *(const f16x8*)(sKh + addr);
                    f16x8 al = *(const f16x8*)(sKl + addr);
#pragma unroll
                    for (int mt = 0; mt < 2; mt++) {
                        S[mt][ks2] = __builtin_amdgcn_mfma_f32_16x16x32_f16(ah, qfh[mt][ksd], S[mt][ks2], 0, 0, 0);
                        S[mt][ks2] = __builtin_amdgcn_mfma_f32_16x16x32_f16(al, qfh[mt][ksd], S[mt][ks2], 0, 0, 0);
                        S[mt][ks2] = __builtin_amdgcn_mfma_f32_16x16x32_f16(ah, qfl[mt][ksd], S[mt][ks2], 0, 0, 0);
                    }
                }
            }
            // poly + fp16 round; consistent denominator; pack PV B-fragments
#pragma unroll
            for (int mt = 0; mt < 2; mt++) {
#pragma unroll
                for (int ks2 = 0; ks2 < 4; ks2++) {
#pragma unroll
                    for (int r = 0; r < 4; r++) {
                        float s = S[mt][ks2][r];
                        float w = fmaxf(fmaf(fmaf(a2, s, b1), s, g0), 0.f);
                        _Float16 wh = (_Float16)w;
                        dsum[mt] += (float)wh;
                        bfrag[mt][ks2][(T << 2) | r] = wh;
                    }
                }
            }
        }

        // ---- O += V^T x P^T (A = V^T frag from LDS, B = bfrag registers) ----
#pragma unroll
        for (int ks2 = 0; ks2 < 4; ks2++) {
#pragma unroll
            for (int dt = 0; dt < 4; dt++) {
                int addr = (((ks2 * 4 + dt) * 64) + quad * 16 + l16) * 8;
                f16x8 vf = *(const f16x8*)(sVt + addr);
#pragma unroll
                for (int mt = 0; mt < 2; mt++)
                    O[dt][mt] = __builtin_amdgcn_mfma_f32_16x16x32_f16(vf, bfrag[mt][ks2], O[dt][mt], 0, 0, 0);
            }
        }
        __syncthreads();   // compute done before next stage overwrites
    }

    // denominator: per-lane partials cover kv rows of this quad -> reduce
    float rinv[2];
#pragma unroll
    for (int mt = 0; mt < 2; mt++) {
        float v = dsum[mt];
        v += __shfl_xor(v, 16);
        v += __shfl_xor(v, 32);
        rinv[mt] = 1.0f / (v + 1e-6f);
    }

    // normalize + store fp32 to outh32[B,N,H*d], float4 per (dt,mt)
    const int base_row = qt * 128 + wv * 32;
#pragma unroll
    for (int dt = 0; dt < 4; dt++) {
#pragma unroll
        for (int mt = 0; mt < 2; mt++) {
            float4 o4;
            o4.x = O[dt][mt][0] * rinv[mt];
            o4.y = O[dt][mt][1] * rinv[mt];
            o4.z = O[dt][mt][2] * rinv[mt];
            o4.w = O[dt][mt][3] * rinv[mt];
            int row = base_row + mt * 16 + l16;                 // token n
            int col = h * ND + dt * 16 + quad * 4;              // channel c
            *(float4*)(outh32 + (size_t)(b * NN + row) * NC + col) = o4;
        }
    }
}

// ---------------- proj GEMM: out = outh32 * Wproj^T + b_proj, 3-term split ----------------
__global__ __launch_bounds__(256) void gemm_proj(
    const float* __restrict__ A,
    const _Float16* __restrict__ Bh, const _Float16* __restrict__ Bl,
    const float* __restrict__ bias, float* __restrict__ out)
{
    __shared__ __align__(16) _Float16 sAh[128 * 32];
    __shared__ __align__(16) _Float16 sAl[128 * 32];
    __shared__ __align__(16) _Float16 sBh[128 * 32];
    __shared__ __align__(16) _Float16 sBl[128 * 32];
    const int tid = threadIdx.x;
    const int lane = tid & 63, wv = tid >> 6;
    const int quad = lane >> 4, l16 = lane & 15;
    const int wm = (wv >> 1) * 64, wn = (wv & 1) * 64;
    const int m0 = blockIdx.x * 128, n0 = blockIdx.y * 128;

    f32x4 acc[4][4] = {};

    for (int k0 = 0; k0 < NC; k0 += 32) {
#pragma unroll
        for (int i = 0; i < 2; i++) {
            int c = tid + i * 256;
            int r = c >> 2, kc = c & 3;
            const float4* pa = (const float4*)(A + (size_t)(m0 + r) * NC + k0 + kc * 8);
            float4 v0 = pa[0], v1 = pa[1];
            f16x8 hi8, lo8;
            hi8[0] = (_Float16)v0.x; lo8[0] = (_Float16)(v0.x - (float)hi8[0]);
            hi8[1] = (_Float16)v0.y; lo8[1] = (_Float16)(v0.y - (float)hi8[1]);
            hi8[2] = (_Float16)v0.z; lo8[2] = (_Float16)(v0.z - (float)hi8[2]);
            hi8[3] = (_Float16)v0.w; lo8[3] = (_Float16)(v0.w - (float)hi8[3]);
            hi8[4] = (_Float16)v1.x; lo8[4] = (_Float16)(v1.x - (float)hi8[4]);
            hi8[5] = (_Float16)v1.y; lo8[5] = (_Float16)(v1.y - (float)hi8[5]);
            hi8[6] = (_Float16)v1.z; lo8[6] = (_Float16)(v1.z - (float)hi8[6]);
            hi8[7] = (_Float16)v1.w; lo8[7] = (_Float16)(v1.w - (float)hi8[7]);
            *(f16x8*)(sAh + c * 8) = hi8;
            *(f16x8*)(sAl + c * 8) = lo8;
            size_t goB = (size_t)(n0 + r) * NC + k0 + kc * 8;
            async16(Bh + goB, sBh + c * 8);
            async16(Bl + goB, sBl + c * 8);
        }
        __syncthreads();
        f16x8 ah[4], al[4], bh[4], bl[4];
#pragma unroll
        for (int t = 0; t < 4; t++) {
            ah[t] = *(const f16x8*)(sAh + (wm + t * 16 + l16) * 32 + quad * 8);
            al[t] = *(const f16x8*)(sAl + (wm + t * 16 + l16) * 32 + quad * 8);
            bh[t] = *(const f16x8*)(sBh + (wn + t * 16 + l16) * 32 + quad * 8);
            bl[t] = *(const f16x8*)(sBl + (wn + t * 16 + l16) * 32 + quad * 8);
        }
#pragma unroll
        for (int i = 0; i < 4; i++)
#pragma unroll
            for (int j = 0; j < 4; j++)
                acc[i][j] = __builtin_amdgcn_mfma_f32_16x16x32_f16(ah[i], bh[j], acc[i][j], 0, 0, 0);
#pragma unroll
        for (int i = 0; i < 4; i++)
#pragma unroll
            for (int j = 0; j < 4; j++)
                acc[i][j] = __builtin_amdgcn_mfma_f32_16x16x32_f16(al[i], bh[j], acc[i][j], 0, 0, 0);
#pragma unroll
        for (int i = 0; i < 4; i++)
#pragma unroll
            for (int j = 0; j < 4; j++)
                acc[i][j] = __builtin_amdgcn_mfma_f32_16x16x32_f16(ah[i], bl[j], acc[i][j], 0, 0, 0);
        __syncthreads();
    }

#pragma unroll
    for (int i = 0; i < 4; i++) {
#pragma unroll
        for (int j = 0; j < 4; j++) {
#pragma unroll
            for (int r = 0; r < 4; r++) {
                int row = m0 + wm + i * 16 + quad * 4 + r;
                int col = n0 + wn + j * 16 + l16;
                out[(size_t)row * NC + col] = acc[i][j][r] + bias[col];
            }
        }
    }
}

// ---------------- launch ----------------
extern "C" void kernel_launch(void* const* d_in, const int* in_sizes, int n_in,
                              void* d_out, int out_size, void* d_ws, size_t ws_size,
                              hipStream_t stream) {
    const float* x      = (const float*)d_in[0];
    const float* w_qkv  = (const float*)d_in[1];
    const float* w_proj = (const float*)d_in[2];
    const float* b_proj = (const float*)d_in[3];
    const float* alpha  = (const float*)d_in[4];
    const float* beta   = (const float*)d_in[5];
    const float* gamma  = (const float*)d_in[6];
    float* out = (float*)d_out;

    char* ws = (char*)d_ws;
    _Float16* xh     = (_Float16*)(ws + 0);            // dead after gemm_qkv
    _Float16* xl     = (_Float16*)(ws + 12582912);     // dead after gemm_qkv
    float*    outh32 = (float*)(ws + 0);               // overlays xh/xl
    _Float16* wqkvh  = (_Float16*)(ws + 25165824);
    _Float16* wqkvl  = (_Float16*)(ws + 28704768);
    _Float16* wprojh = (_Float16*)(ws + 32243712);
    _Float16* wprojl = (_Float16*)(ws + 33423360);
    _Float16* qh     = (_Float16*)(ws + 34603008);
    _Float16* ql     = (_Float16*)(ws + 47185920);
    _Float16* kh     = (_Float16*)(ws + 59768832);
    _Float16* kl     = (_Float16*)(ws + 72351744);
    _Float16* vt16   = (_Float16*)(ws + 84934656);     // ends 97,517,568 B

    cvt_split_f32<<<6144, 256, 0, stream>>>(x, xh, xl, 1572864);
    cvt_split_f32<<<1728, 256, 0, stream>>>(w_qkv, wqkvh, wqkvl, 442368);
    cvt_split_f32<<<576, 256, 0, stream>>>(w_proj, wprojh, wprojl, 147456);

    gemm_qkv<<<dim3(64, 18), 256, 0, stream>>>(xh, xl, wqkvh, wqkvl, qh, ql, kh, kl, vt16);
    attn_kernel<<<dim3(8, 96), 256, 0, stream>>>(qh, ql, kh, kl, vt16, outh32, alpha, beta, gamma);
    gemm_proj<<<dim3(64, 6), 256, 0, stream>>>(outh32, wprojh, wprojl, b_proj, out);
}